// Round 3
// baseline (596.478 us; speedup 1.0000x reference)
//
#include <hip/hip_runtime.h>

// Problem: out[n,:] = concat(x[n,:], mean[batch_id[n],:]) @ W^T + b
//   N ~= 500000, IN = OUT = 128, G = 1024 graphs, batch_id SORTED.
// Fully-fused: one block per graph (self-contained), now 512 threads/block
// (8 waves/CU vs 4 — round-2 counters showed latency-bound at 11.5% occupancy,
// 1.79 TB/s). Phases:
//   B: stream segment rows (fp32), fp32 sums + bf16 LDS staging (XOR-swizzled)
//   C: reduce -> mean; ctx[g] = mean @ W2^T + b (in LDS)
//   D: out[rows] = LDS_A @ W1^T(regs) + ctx.
// Traffic: read x once + write out once (~390 MB measured incl. L3 absorption).

#define G_NUM 1024
#define IN_F 128
#define OUT_F 128
#define BDIM 512
#define CAP 600                              // staged rows (mean 488, sigma ~22)
#define SMEM_HDR 9216                        // red 8192 + ms 512 + ctx 512
#define SMEM_BYTES (SMEM_HDR + CAP * 256)    // 162816 <= 163840 (proven r2)

typedef __attribute__((ext_vector_type(8))) short short8;          // 8 bf16
typedef __attribute__((ext_vector_type(4))) float f32x4;           // MFMA C/D frag
typedef __attribute__((ext_vector_type(4))) unsigned short us4;    // 4 bf16 = 8B

static __device__ __forceinline__ unsigned short f2bf(float f) {
    union { float f; unsigned u; } v; v.f = f;
    unsigned u = v.u;
    return (unsigned short)((u + 0x7FFFu + ((u >> 16) & 1u)) >> 16);  // RNE
}

static __device__ __forceinline__ us4 pack4(float4 a) {
    us4 o;
    o[0] = f2bf(a.x); o[1] = f2bf(a.y); o[2] = f2bf(a.z); o[3] = f2bf(a.w);
    return o;
}

static __device__ __forceinline__ short8 pack8(float4 a, float4 b) {
    short8 o;
    o[0] = (short)f2bf(a.x); o[1] = (short)f2bf(a.y);
    o[2] = (short)f2bf(a.z); o[3] = (short)f2bf(a.w);
    o[4] = (short)f2bf(b.x); o[5] = (short)f2bf(b.y);
    o[6] = (short)f2bf(b.z); o[7] = (short)f2bf(b.w);
    return o;
}

// ---------------------------------------------------------------------------
// Fused kernel: one block per graph, 512 threads, dynamic LDS.
// ---------------------------------------------------------------------------
__global__ __launch_bounds__(BDIM, 1) void k_fused(
        const float* __restrict__ x, const int* __restrict__ bid,
        const float* __restrict__ W, const float* __restrict__ b,
        float* __restrict__ out, int N) {
    extern __shared__ char smem[];
    float4 (*red)[32] = (float4 (*)[32])(smem);      // 16*32*16 = 8192 B
    float* ms   = (float*)(smem + 8192);             // 128 f32 mean
    float* ctxs = (float*)(smem + 8704);             // 128 f32 ctx row
    char* xs    = smem + SMEM_HDR;                   // CAP rows x 256 B (bf16, swizzled)

    int g = blockIdx.x;
    int tid = threadIdx.x;

    // segment bounds in sorted batch_id
    int lo = 0, hi = N;
    while (lo < hi) { int m = (lo + hi) >> 1; if (bid[m] < g) lo = m + 1; else hi = m; }
    int start = lo;
    int lo2 = start, hi2 = N;
    while (lo2 < hi2) { int m = (lo2 + hi2) >> 1; if (bid[m] < g + 1) lo2 = m + 1; else hi2 = m; }
    int end = lo2;
    int cnt = end - start;

    // ---- phase B: stream rows, fp32 sums + bf16 LDS staging ----
    int c4 = tid & 31;          // 16B (fp32 float4) column 0..31
    int rg = tid >> 5;          // row stripe 0..15
    int uu = c4 >> 1;           // 16B bf16 granule 0..15 within row
    int hb = (c4 & 1) * 8;      // byte offset within granule
    float4 s0 = make_float4(0.f, 0.f, 0.f, 0.f);
    float4 s1 = s0, s2 = s0, s3 = s0;

    int r = start + rg;
    for (; r + 48 < end; r += 64) {
        const float* p0 = x + (size_t)r * IN_F + c4 * 4;
        float4 a = *(const float4*)(p0);
        float4 c = *(const float4*)(p0 + 16 * IN_F);
        float4 d = *(const float4*)(p0 + 32 * IN_F);
        float4 e = *(const float4*)(p0 + 48 * IN_F);
        int lr = r - start;
        int sw = ((uu ^ (lr & 7)) << 4) + hb;   // stride-16 rows share lr&7
        if (lr      < CAP) *(us4*)(xs + (size_t)(lr     ) * 256 + sw) = pack4(a);
        if (lr + 16 < CAP) *(us4*)(xs + (size_t)(lr + 16) * 256 + sw) = pack4(c);
        if (lr + 32 < CAP) *(us4*)(xs + (size_t)(lr + 32) * 256 + sw) = pack4(d);
        if (lr + 48 < CAP) *(us4*)(xs + (size_t)(lr + 48) * 256 + sw) = pack4(e);
        s0.x += a.x; s0.y += a.y; s0.z += a.z; s0.w += a.w;
        s1.x += c.x; s1.y += c.y; s1.z += c.z; s1.w += c.w;
        s2.x += d.x; s2.y += d.y; s2.z += d.z; s2.w += d.w;
        s3.x += e.x; s3.y += e.y; s3.z += e.z; s3.w += e.w;
    }
    for (; r < end; r += 16) {
        float4 a = *(const float4*)(x + (size_t)r * IN_F + c4 * 4);
        int lr = r - start;
        if (lr < CAP) *(us4*)(xs + (size_t)lr * 256 + ((uu ^ (lr & 7)) << 4) + hb) = pack4(a);
        s0.x += a.x; s0.y += a.y; s0.z += a.z; s0.w += a.w;
    }
    s0.x += s1.x + s2.x + s3.x;
    s0.y += s1.y + s2.y + s3.y;
    s0.z += s1.z + s2.z + s3.z;
    s0.w += s1.w + s2.w + s3.w;

    red[rg][c4] = s0;
    __syncthreads();

    int lane = tid & 63, wave = tid >> 6;
    int l16 = lane & 15, quad = lane >> 4;

    // ---- W1 -> bf16 register fragments (held across phase D) ----
    short8 bw[4][8];
    #pragma unroll
    for (int kt = 0; kt < 4; ++kt)
        #pragma unroll
        for (int ot = 0; ot < 8; ++ot) {
            const float* wp = W + (size_t)(ot * 16 + l16) * 256 + kt * 32 + quad * 8;
            bw[kt][ot] = pack8(*(const float4*)wp, *(const float4*)(wp + 4));
        }

    // ---- phase C: reduce -> mean; ctx = mean @ W2^T + b ----
    if (tid < 32) {
        float4 t = red[0][tid];
        #pragma unroll
        for (int i = 1; i < 16; ++i) {
            float4 v = red[i][tid];
            t.x += v.x; t.y += v.y; t.z += v.z; t.w += v.w;
        }
        float inv = 1.0f / (float)(cnt > 0 ? cnt : 1);
        ms[tid * 4 + 0] = t.x * inv;
        ms[tid * 4 + 1] = t.y * inv;
        ms[tid * 4 + 2] = t.z * inv;
        ms[tid * 4 + 3] = t.w * inv;
    }
    __syncthreads();
    if (tid < OUT_F) {
        float acc = b[tid];
        const float* w2 = W + (size_t)tid * 256 + 128;
        #pragma unroll 8
        for (int k = 0; k < IN_F; ++k) acc += ms[k] * w2[k];
        ctxs[tid] = acc;
    }
    __syncthreads();

    // ---- phase D: out[rows] = A(LDS bf16) @ W1^T(regs) + ctx ----
    float cv[8];
    #pragma unroll
    for (int ot = 0; ot < 8; ++ot) cv[ot] = ctxs[ot * 16 + l16];

    int ntiles = (cnt + 15) >> 4;
    for (int t = wave; t < ntiles; t += 8) {
        int lr = t * 16 + l16;
        short8 af[4];
        if (lr < cnt && lr < CAP) {
            const char* rp = xs + (size_t)lr * 256;
            int swb = lr & 7;
            #pragma unroll
            for (int kt = 0; kt < 4; ++kt)
                af[kt] = *(const short8*)(rp + (((kt * 4 + quad) ^ swb) << 4));
        } else if (lr < cnt) {
            // spill rows beyond CAP (statistically never): re-read from global
            const float* p = x + (size_t)(start + lr) * IN_F;
            #pragma unroll
            for (int kt = 0; kt < 4; ++kt)
                af[kt] = pack8(*(const float4*)(p + kt * 32 + quad * 8),
                               *(const float4*)(p + kt * 32 + quad * 8 + 4));
        } else {
            #pragma unroll
            for (int kt = 0; kt < 4; ++kt) af[kt] = (short8){0, 0, 0, 0, 0, 0, 0, 0};
        }

        f32x4 acc[8];
        #pragma unroll
        for (int ot = 0; ot < 8; ++ot) acc[ot] = (f32x4){0.f, 0.f, 0.f, 0.f};
        #pragma unroll
        for (int kt = 0; kt < 4; ++kt)
            #pragma unroll
            for (int ot = 0; ot < 8; ++ot)
                acc[ot] = __builtin_amdgcn_mfma_f32_16x16x32_bf16(
                    af[kt], bw[kt][ot], acc[ot], 0, 0, 0);

        #pragma unroll
        for (int r4 = 0; r4 < 4; ++r4) {
            int rl = t * 16 + quad * 4 + r4;
            if (rl < cnt) {
                float* po = out + (size_t)(start + rl) * OUT_F;
                #pragma unroll
                for (int ot = 0; ot < 8; ++ot)
                    po[ot * 16 + l16] = acc[ot][r4] + cv[ot];
            }
        }
    }
}

// ===========================================================================
// Fallback path (round-1 verified): pass1 + bf16 GEMM, used only if the
// dynamic-LDS opt-in fails.
// ===========================================================================
template <bool WXB>
__global__ __launch_bounds__(256) void k_pass1(
        const float* __restrict__ x, const int* __restrict__ bid,
        const float* __restrict__ W, const float* __restrict__ b,
        float* __restrict__ ctx, unsigned short* __restrict__ W1b,
        unsigned short* __restrict__ xb, int N) {
    int g = blockIdx.x;
    int tid = threadIdx.x;

    if (tid < 16) {
        int i = (g << 4) + tid;
        W1b[i] = f2bf(W[(i >> 7) * 256 + (i & 127)]);
    }

    int lo = 0, hi = N;
    while (lo < hi) { int m = (lo + hi) >> 1; if (bid[m] < g) lo = m + 1; else hi = m; }
    int start = lo;
    int lo2 = start, hi2 = N;
    while (lo2 < hi2) { int m = (lo2 + hi2) >> 1; if (bid[m] < g + 1) lo2 = m + 1; else hi2 = m; }
    int end = lo2;
    int cnt = end - start;

    __shared__ float4 red[8][32];
    __shared__ float ms[IN_F];

    int c4 = tid & 31;
    int rg = tid >> 5;
    float4 s0 = make_float4(0.f, 0.f, 0.f, 0.f);
    float4 s1 = s0, s2 = s0, s3 = s0;

    int r = start + rg;
    for (; r + 24 < end; r += 32) {
        float4 a = *(const float4*)(x + (size_t)(r     ) * IN_F + c4 * 4);
        float4 c = *(const float4*)(x + (size_t)(r +  8) * IN_F + c4 * 4);
        float4 d = *(const float4*)(x + (size_t)(r + 16) * IN_F + c4 * 4);
        float4 e = *(const float4*)(x + (size_t)(r + 24) * IN_F + c4 * 4);
        if (WXB) {
            *(us4*)(xb + (size_t)(r     ) * IN_F + c4 * 4) = pack4(a);
            *(us4*)(xb + (size_t)(r +  8) * IN_F + c4 * 4) = pack4(c);
            *(us4*)(xb + (size_t)(r + 16) * IN_F + c4 * 4) = pack4(d);
            *(us4*)(xb + (size_t)(r + 24) * IN_F + c4 * 4) = pack4(e);
        }
        s0.x += a.x; s0.y += a.y; s0.z += a.z; s0.w += a.w;
        s1.x += c.x; s1.y += c.y; s1.z += c.z; s1.w += c.w;
        s2.x += d.x; s2.y += d.y; s2.z += d.z; s2.w += d.w;
        s3.x += e.x; s3.y += e.y; s3.z += e.z; s3.w += e.w;
    }
    for (; r < end; r += 8) {
        float4 a = *(const float4*)(x + (size_t)r * IN_F + c4 * 4);
        if (WXB) *(us4*)(xb + (size_t)r * IN_F + c4 * 4) = pack4(a);
        s0.x += a.x; s0.y += a.y; s0.z += a.z; s0.w += a.w;
    }
    s0.x += s1.x + s2.x + s3.x;
    s0.y += s1.y + s2.y + s3.y;
    s0.z += s1.z + s2.z + s3.z;
    s0.w += s1.w + s2.w + s3.w;

    red[rg][c4] = s0;
    __syncthreads();
    if (tid < 32) {
        float4 t = red[0][tid];
        #pragma unroll
        for (int i = 1; i < 8; ++i) {
            float4 v = red[i][tid];
            t.x += v.x; t.y += v.y; t.z += v.z; t.w += v.w;
        }
        float inv = 1.0f / (float)(cnt > 0 ? cnt : 1);
        ms[tid * 4 + 0] = t.x * inv;
        ms[tid * 4 + 1] = t.y * inv;
        ms[tid * 4 + 2] = t.z * inv;
        ms[tid * 4 + 3] = t.w * inv;
    }
    __syncthreads();
    if (tid < OUT_F) {
        int o = tid;
        float acc = b[o];
        const float* w2 = W + o * 256 + 128;
        #pragma unroll 8
        for (int k = 0; k < IN_F; ++k) acc += ms[k] * w2[k];
        ctx[g * OUT_F + o] = acc;
    }
}

__global__ __launch_bounds__(256, 3) void k_gemm_bf(
        const unsigned short* __restrict__ xb, const int* __restrict__ bid,
        const unsigned short* __restrict__ W1b, const float* __restrict__ ctx,
        float* __restrict__ out, int N) {
    int tid = threadIdx.x;
    int row0 = blockIdx.x * 128;
    int lane = tid & 63, wave = tid >> 6;
    int l16 = lane & 15, quad = lane >> 4;
    int wrow = wave * 32;

    f32x4 acc[2][8];
    #pragma unroll
    for (int mt = 0; mt < 2; ++mt)
        #pragma unroll
        for (int ot = 0; ot < 8; ++ot)
            acc[mt][ot] = (f32x4){0.f, 0.f, 0.f, 0.f};

    #pragma unroll
    for (int kt = 0; kt < 4; ++kt) {
        short8 af[2];
        #pragma unroll
        for (int mt = 0; mt < 2; ++mt) {
            int rrow = row0 + wrow + mt * 16 + l16;
            short8 v = (short8){0, 0, 0, 0, 0, 0, 0, 0};
            if (rrow < N)
                v = *(const short8*)(xb + (size_t)rrow * IN_F + kt * 32 + quad * 8);
            af[mt] = v;
        }
        #pragma unroll
        for (int ot = 0; ot < 8; ++ot) {
            short8 bf = *(const short8*)(W1b + (ot * 16 + l16) * IN_F + kt * 32 + quad * 8);
            acc[0][ot] = __builtin_amdgcn_mfma_f32_16x16x32_bf16(af[0], bf, acc[0][ot], 0, 0, 0);
            acc[1][ot] = __builtin_amdgcn_mfma_f32_16x16x32_bf16(af[1], bf, acc[1][ot], 0, 0, 0);
        }
    }

    int lastrow = row0 + 127 < N ? row0 + 127 : N - 1;
    int b_lo = bid[row0], b_hi = bid[lastrow];
    if (b_lo == b_hi) {
        float cv[8];
        #pragma unroll
        for (int ot = 0; ot < 8; ++ot)
            cv[ot] = ctx[b_lo * OUT_F + ot * 16 + l16];
        #pragma unroll
        for (int mt = 0; mt < 2; ++mt) {
            #pragma unroll
            for (int r4 = 0; r4 < 4; ++r4) {
                int row = row0 + wrow + mt * 16 + quad * 4 + r4;
                if (row < N) {
                    #pragma unroll
                    for (int ot = 0; ot < 8; ++ot)
                        out[(size_t)row * OUT_F + ot * 16 + l16] =
                            acc[mt][ot][r4] + cv[ot];
                }
            }
        }
    } else {
        #pragma unroll
        for (int mt = 0; mt < 2; ++mt) {
            #pragma unroll
            for (int r4 = 0; r4 < 4; ++r4) {
                int row = row0 + wrow + mt * 16 + quad * 4 + r4;
                if (row < N) {
                    int cb = bid[row] * OUT_F;
                    #pragma unroll
                    for (int ot = 0; ot < 8; ++ot)
                        out[(size_t)row * OUT_F + ot * 16 + l16] =
                            acc[mt][ot][r4] + ctx[cb + ot * 16 + l16];
                }
            }
        }
    }
}

// ---------------------------------------------------------------------------
extern "C" void kernel_launch(void* const* d_in, const int* in_sizes, int n_in,
                              void* d_out, int out_size, void* d_ws, size_t ws_size,
                              hipStream_t stream) {
    const float* x  = (const float*)d_in[0];
    const int* bid  = (const int*)d_in[1];
    const float* W  = (const float*)d_in[2];
    const float* b  = (const float*)d_in[3];
    float* out      = (float*)d_out;
    int N = in_sizes[1];

    static int fused_ok = -1;
    if (fused_ok < 0) {
        fused_ok = (hipFuncSetAttribute(
                        reinterpret_cast<const void*>(&k_fused),
                        hipFuncAttributeMaxDynamicSharedMemorySize,
                        SMEM_BYTES) == hipSuccess) ? 1 : 0;
    }

    if (fused_ok) {
        k_fused<<<G_NUM, BDIM, SMEM_BYTES, stream>>>(x, bid, W, b, out, N);
        return;
    }

    // fallback: round-1 verified 2-kernel path (needs workspace)
    size_t ctx_bytes = (size_t)G_NUM * OUT_F * sizeof(float);
    size_t w1b_bytes = (size_t)OUT_F * IN_F * sizeof(unsigned short);
    float* ctx = (float*)d_ws;
    unsigned short* W1b = (unsigned short*)((char*)d_ws + ctx_bytes);
    unsigned short* xb  = (unsigned short*)((char*)d_ws + ctx_bytes + w1b_bytes);

    k_pass1<true><<<G_NUM, 256, 0, stream>>>(x, bid, W, b, ctx, W1b, xb, N);
    k_gemm_bf<<<(N + 127) / 128, 256, 0, stream>>>(xb, bid, W1b, ctx, out, N);
}

// Round 4
// 493.886 us; speedup vs baseline: 1.2077x; 1.2077x over previous
//
#include <hip/hip_runtime.h>

// Problem: out[n,:] = concat(x[n,:], mean[batch_id[n],:]) @ W^T + b
//   N ~= 500000, IN = OUT = 128, G = 1024 graphs, batch_id SORTED.
// Fully-fused: one block per graph (self-contained), 512 threads/block.
// Round-3 lesson: at 512 thr the compiler budgets 128 VGPR; holding all of
// W1 (bw[4][8] = 128 VGPR) spilled to scratch and DOUBLED HBM traffic.
// This round: phase D splits output cols across wave pairs -> bw[4][4]
// (64 VGPR), peak ~115 regs, no spill. Phases:
//   B: stream segment rows (fp32), fp32 sums + bf16 LDS staging (XOR-swizzled)
//   C: reduce -> mean; ctx[g] = mean @ W2^T + b (in LDS)
//   D: wave pair (row-tiles stride 4) x (col half): out = LDS_A @ W1^T + ctx.

#define G_NUM 1024
#define IN_F 128
#define OUT_F 128
#define BDIM 512
#define CAP 600                              // staged rows (mean 488, sigma ~22)
#define SMEM_HDR 9216                        // red 8192 + ms 512 + ctx 512
#define SMEM_BYTES (SMEM_HDR + CAP * 256)    // 162816 <= 163840 (proven r2/r3)

typedef __attribute__((ext_vector_type(8))) short short8;          // 8 bf16
typedef __attribute__((ext_vector_type(4))) float f32x4;           // MFMA C/D frag
typedef __attribute__((ext_vector_type(4))) unsigned short us4;    // 4 bf16 = 8B

static __device__ __forceinline__ unsigned short f2bf(float f) {
    union { float f; unsigned u; } v; v.f = f;
    unsigned u = v.u;
    return (unsigned short)((u + 0x7FFFu + ((u >> 16) & 1u)) >> 16);  // RNE
}

static __device__ __forceinline__ us4 pack4(float4 a) {
    us4 o;
    o[0] = f2bf(a.x); o[1] = f2bf(a.y); o[2] = f2bf(a.z); o[3] = f2bf(a.w);
    return o;
}

static __device__ __forceinline__ short8 pack8(float4 a, float4 b) {
    short8 o;
    o[0] = (short)f2bf(a.x); o[1] = (short)f2bf(a.y);
    o[2] = (short)f2bf(a.z); o[3] = (short)f2bf(a.w);
    o[4] = (short)f2bf(b.x); o[5] = (short)f2bf(b.y);
    o[6] = (short)f2bf(b.z); o[7] = (short)f2bf(b.w);
    return o;
}

// ---------------------------------------------------------------------------
// Fused kernel: one block per graph, 512 threads, dynamic LDS.
// ---------------------------------------------------------------------------
__global__ __launch_bounds__(BDIM, 1) void k_fused(
        const float* __restrict__ x, const int* __restrict__ bid,
        const float* __restrict__ W, const float* __restrict__ b,
        float* __restrict__ out, int N) {
    extern __shared__ char smem[];
    float4 (*red)[32] = (float4 (*)[32])(smem);      // 16*32*16 = 8192 B
    float* ms   = (float*)(smem + 8192);             // 128 f32 mean
    float* ctxs = (float*)(smem + 8704);             // 128 f32 ctx row
    char* xs    = smem + SMEM_HDR;                   // CAP rows x 256 B (bf16, swizzled)

    int g = blockIdx.x;
    int tid = threadIdx.x;

    // segment bounds in sorted batch_id
    int lo = 0, hi = N;
    while (lo < hi) { int m = (lo + hi) >> 1; if (bid[m] < g) lo = m + 1; else hi = m; }
    int start = lo;
    int lo2 = start, hi2 = N;
    while (lo2 < hi2) { int m = (lo2 + hi2) >> 1; if (bid[m] < g + 1) lo2 = m + 1; else hi2 = m; }
    int end = lo2;
    int cnt = end - start;

    // ---- phase B: stream rows, fp32 sums + bf16 LDS staging ----
    int c4 = tid & 31;          // 16B (fp32 float4) column 0..31
    int rg = tid >> 5;          // row stripe 0..15
    int uu = c4 >> 1;           // 16B bf16 granule 0..15 within row
    int hb = (c4 & 1) * 8;      // byte offset within granule
    float4 s0 = make_float4(0.f, 0.f, 0.f, 0.f);
    float4 s1 = s0, s2 = s0, s3 = s0;

    int r = start + rg;
    for (; r + 48 < end; r += 64) {
        const float* p0 = x + (size_t)r * IN_F + c4 * 4;
        float4 a = *(const float4*)(p0);
        float4 c = *(const float4*)(p0 + 16 * IN_F);
        float4 d = *(const float4*)(p0 + 32 * IN_F);
        float4 e = *(const float4*)(p0 + 48 * IN_F);
        int lr = r - start;
        int sw = ((uu ^ (lr & 7)) << 4) + hb;   // stride-16 rows share lr&7
        if (lr      < CAP) *(us4*)(xs + (size_t)(lr     ) * 256 + sw) = pack4(a);
        if (lr + 16 < CAP) *(us4*)(xs + (size_t)(lr + 16) * 256 + sw) = pack4(c);
        if (lr + 32 < CAP) *(us4*)(xs + (size_t)(lr + 32) * 256 + sw) = pack4(d);
        if (lr + 48 < CAP) *(us4*)(xs + (size_t)(lr + 48) * 256 + sw) = pack4(e);
        s0.x += a.x; s0.y += a.y; s0.z += a.z; s0.w += a.w;
        s1.x += c.x; s1.y += c.y; s1.z += c.z; s1.w += c.w;
        s2.x += d.x; s2.y += d.y; s2.z += d.z; s2.w += d.w;
        s3.x += e.x; s3.y += e.y; s3.z += e.z; s3.w += e.w;
    }
    for (; r < end; r += 16) {
        float4 a = *(const float4*)(x + (size_t)r * IN_F + c4 * 4);
        int lr = r - start;
        if (lr < CAP) *(us4*)(xs + (size_t)lr * 256 + ((uu ^ (lr & 7)) << 4) + hb) = pack4(a);
        s0.x += a.x; s0.y += a.y; s0.z += a.z; s0.w += a.w;
    }
    s0.x += s1.x + s2.x + s3.x;
    s0.y += s1.y + s2.y + s3.y;
    s0.z += s1.z + s2.z + s3.z;
    s0.w += s1.w + s2.w + s3.w;

    red[rg][c4] = s0;
    __syncthreads();

    int lane = tid & 63, wave = tid >> 6;
    int l16 = lane & 15, quad = lane >> 4;
    int wcol = (wave & 1) * 64;   // wave pair: col half
    int wt   = wave >> 1;         // row-tile stream 0..3

    // ---- W1 col-half -> bf16 register fragments (held across phase D) ----
    // bw[4][4] = 64 VGPRs: fits the 128-VGPR budget, no spill (r3 lesson).
    short8 bw[4][4];
    #pragma unroll
    for (int kt = 0; kt < 4; ++kt)
        #pragma unroll
        for (int ot = 0; ot < 4; ++ot) {
            const float* wp = W + (size_t)(wcol + ot * 16 + l16) * 256 + kt * 32 + quad * 8;
            bw[kt][ot] = pack8(*(const float4*)wp, *(const float4*)(wp + 4));
        }

    // ---- phase C: reduce -> mean; ctx = mean @ W2^T + b ----
    if (tid < 32) {
        float4 t = red[0][tid];
        #pragma unroll
        for (int i = 1; i < 16; ++i) {
            float4 v = red[i][tid];
            t.x += v.x; t.y += v.y; t.z += v.z; t.w += v.w;
        }
        float inv = 1.0f / (float)(cnt > 0 ? cnt : 1);
        ms[tid * 4 + 0] = t.x * inv;
        ms[tid * 4 + 1] = t.y * inv;
        ms[tid * 4 + 2] = t.z * inv;
        ms[tid * 4 + 3] = t.w * inv;
    }
    __syncthreads();
    if (tid < OUT_F) {
        float acc = b[tid];
        const float* w2 = W + (size_t)tid * 256 + 128;
        #pragma unroll 8
        for (int k = 0; k < IN_F; ++k) acc += ms[k] * w2[k];
        ctxs[tid] = acc;
    }
    __syncthreads();

    // ---- phase D: out[rows, colhalf] = A(LDS bf16) @ W1^T(regs) + ctx ----
    float cv[4];
    #pragma unroll
    for (int ot = 0; ot < 4; ++ot) cv[ot] = ctxs[wcol + ot * 16 + l16];

    int ntiles = (cnt + 15) >> 4;
    for (int t = wt; t < ntiles; t += 4) {
        int lr = t * 16 + l16;
        short8 af[4];
        if (lr < cnt && lr < CAP) {
            const char* rp = xs + (size_t)lr * 256;
            int swb = lr & 7;
            #pragma unroll
            for (int kt = 0; kt < 4; ++kt)
                af[kt] = *(const short8*)(rp + (((kt * 4 + quad) ^ swb) << 4));
        } else if (lr < cnt) {
            // spill rows beyond CAP (statistically never): re-read from global
            const float* p = x + (size_t)(start + lr) * IN_F;
            #pragma unroll
            for (int kt = 0; kt < 4; ++kt)
                af[kt] = pack8(*(const float4*)(p + kt * 32 + quad * 8),
                               *(const float4*)(p + kt * 32 + quad * 8 + 4));
        } else {
            #pragma unroll
            for (int kt = 0; kt < 4; ++kt) af[kt] = (short8){0, 0, 0, 0, 0, 0, 0, 0};
        }

        f32x4 acc[4];
        #pragma unroll
        for (int ot = 0; ot < 4; ++ot) acc[ot] = (f32x4){0.f, 0.f, 0.f, 0.f};
        #pragma unroll
        for (int kt = 0; kt < 4; ++kt)
            #pragma unroll
            for (int ot = 0; ot < 4; ++ot)
                acc[ot] = __builtin_amdgcn_mfma_f32_16x16x32_bf16(
                    af[kt], bw[kt][ot], acc[ot], 0, 0, 0);

        #pragma unroll
        for (int r4 = 0; r4 < 4; ++r4) {
            int rl = t * 16 + quad * 4 + r4;
            if (rl < cnt) {
                float* po = out + (size_t)(start + rl) * OUT_F + wcol;
                #pragma unroll
                for (int ot = 0; ot < 4; ++ot)
                    po[ot * 16 + l16] = acc[ot][r4] + cv[ot];
            }
        }
    }
}

// ===========================================================================
// Fallback path (round-1 verified): pass1 + bf16 GEMM, used only if the
// dynamic-LDS opt-in fails.
// ===========================================================================
template <bool WXB>
__global__ __launch_bounds__(256) void k_pass1(
        const float* __restrict__ x, const int* __restrict__ bid,
        const float* __restrict__ W, const float* __restrict__ b,
        float* __restrict__ ctx, unsigned short* __restrict__ W1b,
        unsigned short* __restrict__ xb, int N) {
    int g = blockIdx.x;
    int tid = threadIdx.x;

    if (tid < 16) {
        int i = (g << 4) + tid;
        W1b[i] = f2bf(W[(i >> 7) * 256 + (i & 127)]);
    }

    int lo = 0, hi = N;
    while (lo < hi) { int m = (lo + hi) >> 1; if (bid[m] < g) lo = m + 1; else hi = m; }
    int start = lo;
    int lo2 = start, hi2 = N;
    while (lo2 < hi2) { int m = (lo2 + hi2) >> 1; if (bid[m] < g + 1) lo2 = m + 1; else hi2 = m; }
    int end = lo2;
    int cnt = end - start;

    __shared__ float4 red[8][32];
    __shared__ float ms[IN_F];

    int c4 = tid & 31;
    int rg = tid >> 5;
    float4 s0 = make_float4(0.f, 0.f, 0.f, 0.f);
    float4 s1 = s0, s2 = s0, s3 = s0;

    int r = start + rg;
    for (; r + 24 < end; r += 32) {
        float4 a = *(const float4*)(x + (size_t)(r     ) * IN_F + c4 * 4);
        float4 c = *(const float4*)(x + (size_t)(r +  8) * IN_F + c4 * 4);
        float4 d = *(const float4*)(x + (size_t)(r + 16) * IN_F + c4 * 4);
        float4 e = *(const float4*)(x + (size_t)(r + 24) * IN_F + c4 * 4);
        if (WXB) {
            *(us4*)(xb + (size_t)(r     ) * IN_F + c4 * 4) = pack4(a);
            *(us4*)(xb + (size_t)(r +  8) * IN_F + c4 * 4) = pack4(c);
            *(us4*)(xb + (size_t)(r + 16) * IN_F + c4 * 4) = pack4(d);
            *(us4*)(xb + (size_t)(r + 24) * IN_F + c4 * 4) = pack4(e);
        }
        s0.x += a.x; s0.y += a.y; s0.z += a.z; s0.w += a.w;
        s1.x += c.x; s1.y += c.y; s1.z += c.z; s1.w += c.w;
        s2.x += d.x; s2.y += d.y; s2.z += d.z; s2.w += d.w;
        s3.x += e.x; s3.y += e.y; s3.z += e.z; s3.w += e.w;
    }
    for (; r < end; r += 8) {
        float4 a = *(const float4*)(x + (size_t)r * IN_F + c4 * 4);
        if (WXB) *(us4*)(xb + (size_t)r * IN_F + c4 * 4) = pack4(a);
        s0.x += a.x; s0.y += a.y; s0.z += a.z; s0.w += a.w;
    }
    s0.x += s1.x + s2.x + s3.x;
    s0.y += s1.y + s2.y + s3.y;
    s0.z += s1.z + s2.z + s3.z;
    s0.w += s1.w + s2.w + s3.w;

    red[rg][c4] = s0;
    __syncthreads();
    if (tid < 32) {
        float4 t = red[0][tid];
        #pragma unroll
        for (int i = 1; i < 8; ++i) {
            float4 v = red[i][tid];
            t.x += v.x; t.y += v.y; t.z += v.z; t.w += v.w;
        }
        float inv = 1.0f / (float)(cnt > 0 ? cnt : 1);
        ms[tid * 4 + 0] = t.x * inv;
        ms[tid * 4 + 1] = t.y * inv;
        ms[tid * 4 + 2] = t.z * inv;
        ms[tid * 4 + 3] = t.w * inv;
    }
    __syncthreads();
    if (tid < OUT_F) {
        int o = tid;
        float acc = b[o];
        const float* w2 = W + o * 256 + 128;
        #pragma unroll 8
        for (int k = 0; k < IN_F; ++k) acc += ms[k] * w2[k];
        ctx[g * OUT_F + o] = acc;
    }
}

__global__ __launch_bounds__(256, 3) void k_gemm_bf(
        const unsigned short* __restrict__ xb, const int* __restrict__ bid,
        const unsigned short* __restrict__ W1b, const float* __restrict__ ctx,
        float* __restrict__ out, int N) {
    int tid = threadIdx.x;
    int row0 = blockIdx.x * 128;
    int lane = tid & 63, wave = tid >> 6;
    int l16 = lane & 15, quad = lane >> 4;
    int wrow = wave * 32;

    f32x4 acc[2][8];
    #pragma unroll
    for (int mt = 0; mt < 2; ++mt)
        #pragma unroll
        for (int ot = 0; ot < 8; ++ot)
            acc[mt][ot] = (f32x4){0.f, 0.f, 0.f, 0.f};

    #pragma unroll
    for (int kt = 0; kt < 4; ++kt) {
        short8 af[2];
        #pragma unroll
        for (int mt = 0; mt < 2; ++mt) {
            int rrow = row0 + wrow + mt * 16 + l16;
            short8 v = (short8){0, 0, 0, 0, 0, 0, 0, 0};
            if (rrow < N)
                v = *(const short8*)(xb + (size_t)rrow * IN_F + kt * 32 + quad * 8);
            af[mt] = v;
        }
        #pragma unroll
        for (int ot = 0; ot < 8; ++ot) {
            short8 bf = *(const short8*)(W1b + (ot * 16 + l16) * IN_F + kt * 32 + quad * 8);
            acc[0][ot] = __builtin_amdgcn_mfma_f32_16x16x32_bf16(af[0], bf, acc[0][ot], 0, 0, 0);
            acc[1][ot] = __builtin_amdgcn_mfma_f32_16x16x32_bf16(af[1], bf, acc[1][ot], 0, 0, 0);
        }
    }

    int lastrow = row0 + 127 < N ? row0 + 127 : N - 1;
    int b_lo = bid[row0], b_hi = bid[lastrow];
    if (b_lo == b_hi) {
        float cv[8];
        #pragma unroll
        for (int ot = 0; ot < 8; ++ot)
            cv[ot] = ctx[b_lo * OUT_F + ot * 16 + l16];
        #pragma unroll
        for (int mt = 0; mt < 2; ++mt) {
            #pragma unroll
            for (int r4 = 0; r4 < 4; ++r4) {
                int row = row0 + wrow + mt * 16 + quad * 4 + r4;
                if (row < N) {
                    #pragma unroll
                    for (int ot = 0; ot < 8; ++ot)
                        out[(size_t)row * OUT_F + ot * 16 + l16] =
                            acc[mt][ot][r4] + cv[ot];
                }
            }
        }
    } else {
        #pragma unroll
        for (int mt = 0; mt < 2; ++mt) {
            #pragma unroll
            for (int r4 = 0; r4 < 4; ++r4) {
                int row = row0 + wrow + mt * 16 + quad * 4 + r4;
                if (row < N) {
                    int cb = bid[row] * OUT_F;
                    #pragma unroll
                    for (int ot = 0; ot < 8; ++ot)
                        out[(size_t)row * OUT_F + ot * 16 + l16] =
                            acc[mt][ot][r4] + ctx[cb + ot * 16 + l16];
                }
            }
        }
    }
}

// ---------------------------------------------------------------------------
extern "C" void kernel_launch(void* const* d_in, const int* in_sizes, int n_in,
                              void* d_out, int out_size, void* d_ws, size_t ws_size,
                              hipStream_t stream) {
    const float* x  = (const float*)d_in[0];
    const int* bid  = (const int*)d_in[1];
    const float* W  = (const float*)d_in[2];
    const float* b  = (const float*)d_in[3];
    float* out      = (float*)d_out;
    int N = in_sizes[1];

    static int fused_ok = -1;
    if (fused_ok < 0) {
        fused_ok = (hipFuncSetAttribute(
                        reinterpret_cast<const void*>(&k_fused),
                        hipFuncAttributeMaxDynamicSharedMemorySize,
                        SMEM_BYTES) == hipSuccess) ? 1 : 0;
    }

    if (fused_ok) {
        k_fused<<<G_NUM, BDIM, SMEM_BYTES, stream>>>(x, bid, W, b, out, N);
        return;
    }

    // fallback: round-1 verified 2-kernel path (needs workspace)
    size_t ctx_bytes = (size_t)G_NUM * OUT_F * sizeof(float);
    size_t w1b_bytes = (size_t)OUT_F * IN_F * sizeof(unsigned short);
    float* ctx = (float*)d_ws;
    unsigned short* W1b = (unsigned short*)((char*)d_ws + ctx_bytes);
    unsigned short* xb  = (unsigned short*)((char*)d_ws + ctx_bytes + w1b_bytes);

    k_pass1<true><<<G_NUM, 256, 0, stream>>>(x, bid, W, b, ctx, W1b, xb, N);
    k_gemm_bf<<<(N + 127) / 128, 256, 0, stream>>>(xb, bid, W1b, ctx, out, N);
}